// Round 1
// baseline (158.029 us; speedup 1.0000x reference)
//
#include <hip/hip_runtime.h>
#include <math.h>

#define NN 8192
#define KDIM 256
#define DD 64
#define LRALPHA 0.2f

// ---------------- K1: Wh = h@W  (+ Wh1 = Wh@a1, Wh2 = Wh@a2 fused) ----------------
// 512 blocks x 256 threads; block handles 16 rows; wave handles 4 rows.
__global__ __launch_bounds__(256) void k_gemm(
    const float* __restrict__ h, const float* __restrict__ W,
    const float* __restrict__ a,
    float* __restrict__ Wh, float* __restrict__ Wh1, float* __restrict__ Wh2)
{
    __shared__ float sh[16][KDIM];   // 16 KB
    int t = threadIdx.x;
    int rowBase = blockIdx.x * 16;
    for (int i = t; i < 16 * KDIM / 4; i += 256)
        ((float4*)sh)[i] = ((const float4*)(h + (size_t)rowBase * KDIM))[i];
    __syncthreads();

    int wave = t >> 6, lane = t & 63;
    int r0 = wave * 4;
    float acc0 = 0.f, acc1 = 0.f, acc2 = 0.f, acc3 = 0.f;
    #pragma unroll 8
    for (int k = 0; k < KDIM; ++k) {
        float wk = W[k * DD + lane];          // coalesced, L1/L2-hot (W = 64 KB)
        acc0 = fmaf(sh[r0 + 0][k], wk, acc0);
        acc1 = fmaf(sh[r0 + 1][k], wk, acc1);
        acc2 = fmaf(sh[r0 + 2][k], wk, acc2);
        acc3 = fmaf(sh[r0 + 3][k], wk, acc3);
    }
    float a1 = a[lane], a2 = a[DD + lane];
    float accs[4] = {acc0, acc1, acc2, acc3};
    #pragma unroll
    for (int i = 0; i < 4; ++i) {
        int row = rowBase + r0 + i;
        Wh[(size_t)row * DD + lane] = accs[i];
        float r1 = accs[i] * a1, r2 = accs[i] * a2;
        #pragma unroll
        for (int off = 32; off > 0; off >>= 1) {
            r1 += __shfl_xor(r1, off, 64);
            r2 += __shfl_xor(r2, off, 64);
        }
        if (lane == 0) { Wh1[row] = r1; Wh2[row] = r2; }
    }
}

// ---------------- K2: bitonic sort of Wh2 (single block), emit weights ----------------
__global__ __launch_bounds__(1024) void k_sort(
    const float* __restrict__ Wh2,
    float* __restrict__ sv, int* __restrict__ sidx,
    float* __restrict__ wn, float* __restrict__ wp,
    float* __restrict__ M2out)
{
    __shared__ float v[NN];             // 32 KB
    __shared__ unsigned short ix[NN];   // 16 KB
    int t = threadIdx.x;
    for (int i = t; i < NN; i += 1024) { v[i] = Wh2[i]; ix[i] = (unsigned short)i; }
    __syncthreads();
    for (int size = 2; size <= NN; size <<= 1) {
        for (int stride = size >> 1; stride > 0; stride >>= 1) {
            for (int p = t; p < NN / 2; p += 1024) {
                int low = p & (stride - 1);
                int i = ((p & ~(stride - 1)) << 1) | low;
                int j = i + stride;
                bool up = ((i & size) == 0);
                float vi = v[i], vj = v[j];
                if ((vi > vj) == up) {
                    v[i] = vj; v[j] = vi;
                    unsigned short tmp = ix[i]; ix[i] = ix[j]; ix[j] = tmp;
                }
            }
            __syncthreads();
        }
    }
    float m2 = v[NN - 1];               // global max of Wh2
    for (int i = t; i < NN; i += 1024) {
        float vi = v[i];
        sv[i] = vi;
        sidx[i] = (int)ix[i];
        wn[i] = expf(LRALPHA * (vi - m2));  // <= 1
        wp[i] = expf(vi - m2);              // <= 1
    }
    if (t == 0) M2out[0] = m2;
}

// ---------------- K3: per-64-element-chunk partial sums (128 chunks) ----------------
__global__ __launch_bounds__(256) void k_chunksum(
    const float* __restrict__ Wh, const int* __restrict__ sidx,
    const float* __restrict__ wn, const float* __restrict__ wp,
    float* __restrict__ cs_neg, float* __restrict__ cs_pos,
    float* __restrict__ cs_sn, float* __restrict__ cs_sp)
{
    int t = threadIdx.x, wave = t >> 6, lane = t & 63;
    int ch = blockIdx.x * 4 + wave;     // 0..127
    int base = ch * 64;
    float an = 0.f, ap = 0.f, sn = 0.f, sp = 0.f;
    for (int kk = 0; kk < 64; ++kk) {
        int k = base + kk;
        int j = sidx[k];
        float g = Wh[(size_t)j * DD + lane];
        float wnk = wn[k], wpk = wp[k];
        an = fmaf(wnk, g, an); ap = fmaf(wpk, g, ap);
        sn += wnk; sp += wpk;
    }
    cs_neg[ch * DD + lane] = an;
    cs_pos[ch * DD + lane] = ap;
    if (lane == 0) { cs_sn[ch] = sn; cs_sp[ch] = sp; }
}

// ---------------- K4: scan the 128 chunk sums (tiny) ----------------
__global__ __launch_bounds__(64) void k_scanchunks(
    const float* __restrict__ cs_neg, const float* __restrict__ cs_pos,
    const float* __restrict__ cs_sn, const float* __restrict__ cs_sp,
    float* __restrict__ co_neg, float* __restrict__ co_pos,
    float* __restrict__ co_sn, float* __restrict__ co_sp)
{
    int lane = threadIdx.x;
    float acn = 0.f;
    for (int c = 0; c < 128; ++c) { co_neg[c * DD + lane] = acn; acn += cs_neg[c * DD + lane]; }
    float acp = 0.f;
    for (int c = 127; c >= 0; --c) { co_pos[c * DD + lane] = acp; acp += cs_pos[c * DD + lane]; }
    if (lane == 0) {
        float x = 0.f; for (int c = 0; c < 128; ++c) { co_sn[c] = x; x += cs_sn[c]; }
        float y = 0.f; for (int c = 127; c >= 0; --c) { co_sp[c] = y; y += cs_sp[c]; }
    }
}

// ---------------- K5: write full prefix (neg) / suffix (pos) arrays ----------------
__global__ __launch_bounds__(256) void k_scanwrite(
    const float* __restrict__ Wh, const int* __restrict__ sidx,
    const float* __restrict__ wn, const float* __restrict__ wp,
    const float* __restrict__ co_neg, const float* __restrict__ co_pos,
    const float* __restrict__ co_sn, const float* __restrict__ co_sp,
    float* __restrict__ P_neg, float* __restrict__ S_pos,
    float* __restrict__ s_neg, float* __restrict__ s_pos)
{
    int t = threadIdx.x, wave = t >> 6, lane = t & 63;
    int ch = blockIdx.x * 4 + wave;     // 0..127
    int base = ch * 64;

    // forward exclusive prefix of neg-weighted values
    float acc = co_neg[ch * DD + lane];
    float accs = co_sn[ch];
    for (int kk = 0; kk < 64; ++kk) {
        int k = base + kk;
        int j = sidx[k];
        float g = Wh[(size_t)j * DD + lane];
        P_neg[(size_t)k * DD + lane] = acc;
        if (lane == 0) s_neg[k] = accs;
        float wnk = wn[k];
        acc = fmaf(wnk, g, acc);
        accs += wnk;
    }
    if (ch == 127) {
        P_neg[(size_t)NN * DD + lane] = acc;
        if (lane == 0) s_neg[NN] = accs;
    }

    // backward inclusive suffix of pos-weighted values
    float accp = co_pos[ch * DD + lane];
    float accps = co_sp[ch];
    for (int kk = 63; kk >= 0; --kk) {
        int k = base + kk;
        int j = sidx[k];
        float g = Wh[(size_t)j * DD + lane];
        float wpk = wp[k];
        accp = fmaf(wpk, g, accp);
        accps += wpk;
        S_pos[(size_t)k * DD + lane] = accp;
        if (lane == 0) s_pos[k] = accps;
    }
    if (ch == 127) {
        S_pos[(size_t)NN * DD + lane] = 0.f;
        if (lane == 0) s_pos[NN] = 0.f;
    }
}

// ---------------- K6: per-row binary search + combine + elu ----------------
__global__ __launch_bounds__(256) void k_out(
    const float* __restrict__ Wh1, const float* __restrict__ sv,
    const float* __restrict__ P_neg, const float* __restrict__ S_pos,
    const float* __restrict__ s_neg, const float* __restrict__ s_pos,
    const float* __restrict__ M2p, float* __restrict__ out)
{
    int t = threadIdx.x, wave = t >> 6, lane = t & 63;
    int row = blockIdx.x * 4 + wave;
    float M2 = M2p[0];
    float w1 = Wh1[row];
    float z = w1 + M2;                         // max_j (Wh1_i + Wh2_j)
    float m = (z >= 0.f) ? z : LRALPHA * z;    // lrelu(z) = exact row max of e
    float c1 = expf(z - m);                    // exponent <= 0 always
    float c2 = expf(LRALPHA * z - m);          // exponent <= 0 always
    float tt = -w1;
    // p = #{j : sv[j] <= tt}  (upper bound; ties contribute identically either way)
    int lo = 0, hi = NN;
    while (lo < hi) {
        int mid = (lo + hi) >> 1;
        if (sv[mid] <= tt) lo = mid + 1; else hi = mid;
    }
    int p = lo;
    float num = c2 * P_neg[(size_t)p * DD + lane] + c1 * S_pos[(size_t)p * DD + lane];
    float den = c2 * s_neg[p] + c1 * s_pos[p];
    float r = num / den;
    out[(size_t)row * DD + lane] = (r > 0.f) ? r : expm1f(r);   // elu, alpha=1
}

extern "C" void kernel_launch(void* const* d_in, const int* in_sizes, int n_in,
                              void* d_out, int out_size, void* d_ws, size_t ws_size,
                              hipStream_t stream)
{
    const float* h = (const float*)d_in[0];
    // d_in[1] = adj (bool, unused by the reference computation)
    const float* W = (const float*)d_in[2];
    const float* a = (const float*)d_in[3];
    float* out = (float*)d_out;
    float* ws = (float*)d_ws;

    float* Wh     = ws;                              // NN*DD
    float* Wh1    = Wh + (size_t)NN * DD;            // NN
    float* Wh2    = Wh1 + NN;                        // NN
    float* sv     = Wh2 + NN;                        // NN
    float* wn     = sv + NN;                         // NN
    float* wp     = wn + NN;                         // NN
    float* s_neg  = wp + NN;                         // NN+1
    float* s_pos  = s_neg + (NN + 1);                // NN+1
    float* cs_neg = s_pos + (NN + 1);                // 128*DD
    float* cs_pos = cs_neg + 128 * DD;               // 128*DD
    float* cs_sn  = cs_pos + 128 * DD;               // 128
    float* cs_sp  = cs_sn + 128;                     // 128
    float* co_neg = cs_sp + 128;                     // 128*DD
    float* co_pos = co_neg + 128 * DD;               // 128*DD
    float* co_sn  = co_pos + 128 * DD;               // 128
    float* co_sp  = co_sn + 128;                     // 128
    float* M2     = co_sp + 128;                     // 1
    float* P_neg  = M2 + 1;                          // (NN+1)*DD
    float* S_pos  = P_neg + (size_t)(NN + 1) * DD;   // (NN+1)*DD
    int*   sidx   = (int*)(S_pos + (size_t)(NN + 1) * DD);  // NN ints

    k_gemm<<<NN / 16, 256, 0, stream>>>(h, W, a, Wh, Wh1, Wh2);
    k_sort<<<1, 1024, 0, stream>>>(Wh2, sv, sidx, wn, wp, M2);
    k_chunksum<<<32, 256, 0, stream>>>(Wh, sidx, wn, wp, cs_neg, cs_pos, cs_sn, cs_sp);
    k_scanchunks<<<1, 64, 0, stream>>>(cs_neg, cs_pos, cs_sn, cs_sp, co_neg, co_pos, co_sn, co_sp);
    k_scanwrite<<<32, 256, 0, stream>>>(Wh, sidx, wn, wp, co_neg, co_pos, co_sn, co_sp,
                                        P_neg, S_pos, s_neg, s_pos);
    k_out<<<NN / 4, 256, 0, stream>>>(Wh1, sv, P_neg, S_pos, s_neg, s_pos, M2, out);
}

// Round 2
// 131.475 us; speedup vs baseline: 1.2020x; 1.2020x over previous
//
#include <hip/hip_runtime.h>
#include <math.h>

#define NN 8192
#define KDIM 256
#define DD 64
#define NB 4096
#define LRALPHA 0.2f

__device__ __forceinline__ unsigned f2k(float f) {
    unsigned u = __float_as_uint(f);
    return u ^ ((u >> 31) ? 0xFFFFFFFFu : 0x80000000u);
}
__device__ __forceinline__ float k2f(unsigned k) {
    return __uint_as_float((k & 0x80000000u) ? (k ^ 0x80000000u) : ~k);
}
// monotone non-decreasing key->bucket map (identical formula everywhere)
__device__ __forceinline__ unsigned bucket_of(unsigned key, unsigned kmin, float scale) {
    unsigned d = key - kmin;
    unsigned b = (unsigned)((float)d * scale);
    return b > (NB - 1) ? (NB - 1) : b;
}

// ---------------- K1: Wh = h@W (+ Wh1, Wh2 fused). 1024 blocks x 256 thr, 8 rows/block ----------------
__global__ __launch_bounds__(256) void k_gemm(
    const float* __restrict__ h, const float* __restrict__ W,
    const float* __restrict__ a,
    float* __restrict__ Wh, float* __restrict__ Wh1, float* __restrict__ Wh2)
{
    __shared__ float sh[8][KDIM];   // 8 KB
    int t = threadIdx.x;
    int rowBase = blockIdx.x * 8;
    for (int i = t; i < 8 * KDIM / 4; i += 256)
        ((float4*)sh)[i] = ((const float4*)(h + (size_t)rowBase * KDIM))[i];
    __syncthreads();

    int wave = t >> 6, lane = t & 63;
    int r0 = wave * 2;
    float acc0 = 0.f, acc1 = 0.f;
    #pragma unroll 4
    for (int k4 = 0; k4 < KDIM; k4 += 4) {
        float4 h0 = *(const float4*)&sh[r0 + 0][k4];
        float4 h1 = *(const float4*)&sh[r0 + 1][k4];
        float w0 = W[(k4 + 0) * DD + lane];
        float w1 = W[(k4 + 1) * DD + lane];
        float w2 = W[(k4 + 2) * DD + lane];
        float w3 = W[(k4 + 3) * DD + lane];
        acc0 = fmaf(h0.x, w0, acc0); acc0 = fmaf(h0.y, w1, acc0);
        acc0 = fmaf(h0.z, w2, acc0); acc0 = fmaf(h0.w, w3, acc0);
        acc1 = fmaf(h1.x, w0, acc1); acc1 = fmaf(h1.y, w1, acc1);
        acc1 = fmaf(h1.z, w2, acc1); acc1 = fmaf(h1.w, w3, acc1);
    }
    float a1 = a[lane], a2 = a[DD + lane];
    float accs[2] = {acc0, acc1};
    #pragma unroll
    for (int i = 0; i < 2; ++i) {
        int row = rowBase + r0 + i;
        Wh[(size_t)row * DD + lane] = accs[i];
        float r1 = accs[i] * a1, r2 = accs[i] * a2;
        #pragma unroll
        for (int off = 32; off > 0; off >>= 1) {
            r1 += __shfl_xor(r1, off, 64);
            r2 += __shfl_xor(r2, off, 64);
        }
        if (lane == 0) { Wh1[row] = r1; Wh2[row] = r2; }
    }
}

// ---------------- K2: counting-sort Wh2 into 4096 monotone buckets (1 block) ----------------
__global__ __launch_bounds__(1024) void k_bucket(
    const float* __restrict__ Wh2,
    float* __restrict__ sv, int* __restrict__ sidx,
    float* __restrict__ wn, float* __restrict__ wp,
    int* __restrict__ bstart, float* __restrict__ meta)
{
    __shared__ float v[NN];        // 32 KB
    __shared__ int hist[NB];       // 16 KB
    __shared__ unsigned redmin[16], redmax[16];
    __shared__ int wsum[16];
    int t = threadIdx.x, lane = t & 63, wv = t >> 6;

    unsigned lmin = 0xFFFFFFFFu, lmax = 0u;
    for (int i = t; i < NN; i += 1024) {
        float x = Wh2[i];
        v[i] = x;
        unsigned k = f2k(x);
        lmin = min(lmin, k); lmax = max(lmax, k);
    }
    for (int i = t; i < NB; i += 1024) hist[i] = 0;
    #pragma unroll
    for (int off = 32; off > 0; off >>= 1) {
        lmin = min(lmin, (unsigned)__shfl_xor((int)lmin, off, 64));
        lmax = max(lmax, (unsigned)__shfl_xor((int)lmax, off, 64));
    }
    if (lane == 0) { redmin[wv] = lmin; redmax[wv] = lmax; }
    __syncthreads();
    if (t == 0) {
        unsigned mn = redmin[0], mx = redmax[0];
        for (int i = 1; i < 16; ++i) { mn = min(mn, redmin[i]); mx = max(mx, redmax[i]); }
        redmin[0] = mn; redmax[0] = mx;
    }
    __syncthreads();
    unsigned kmin = redmin[0], kmax = redmax[0];
    float scale = (float)NB / ((float)(kmax - kmin) + 1.0f);
    float M2 = k2f(kmax);   // global max of Wh2

    for (int i = t; i < NN; i += 1024)
        atomicAdd(&hist[bucket_of(f2k(v[i]), kmin, scale)], 1);
    __syncthreads();

    // exclusive scan of hist: 4 bins/thread + wave scan + wave-total scan
    int s0 = hist[4 * t + 0], s1 = hist[4 * t + 1], s2 = hist[4 * t + 2], s3 = hist[4 * t + 3];
    int tot = s0 + s1 + s2 + s3;
    int x = tot;
    #pragma unroll
    for (int off = 1; off < 64; off <<= 1) {
        int y = __shfl_up(x, off, 64);
        if (lane >= off) x += y;
    }
    if (lane == 63) wsum[wv] = x;
    __syncthreads();
    if (t == 0) { int acc = 0; for (int i = 0; i < 16; ++i) { int b = wsum[i]; wsum[i] = acc; acc += b; } }
    __syncthreads();
    int excl = wsum[wv] + (x - tot);
    int e0 = excl, e1 = excl + s0, e2 = e1 + s1, e3 = e2 + s2;
    hist[4 * t + 0] = e0; hist[4 * t + 1] = e1; hist[4 * t + 2] = e2; hist[4 * t + 3] = e3;
    bstart[4 * t + 0] = e0; bstart[4 * t + 1] = e1; bstart[4 * t + 2] = e2; bstart[4 * t + 3] = e3;
    if (t == 0) {
        bstart[NB] = NN;
        meta[0] = M2; meta[1] = __uint_as_float(kmin); meta[2] = scale;
    }
    __syncthreads();

    // scatter (bucket-ordered; in-bucket order arbitrary)
    for (int i = t; i < NN; i += 1024) {
        float xv = v[i];
        unsigned b = bucket_of(f2k(xv), kmin, scale);
        int pos = atomicAdd(&hist[b], 1);
        sv[pos] = xv;
        sidx[pos] = i;
        wn[pos] = expf(LRALPHA * (xv - M2));   // <= 1
        wp[pos] = expf(xv - M2);               // <= 1
    }
}

// ---------------- K3: per-64-element-chunk partial sums (128 chunks) ----------------
__global__ __launch_bounds__(256) void k_chunksum(
    const float* __restrict__ Wh, const int* __restrict__ sidx,
    const float* __restrict__ wn, const float* __restrict__ wp,
    float* __restrict__ cs_neg, float* __restrict__ cs_pos,
    float* __restrict__ cs_sn, float* __restrict__ cs_sp)
{
    int t = threadIdx.x, wave = t >> 6, lane = t & 63;
    int ch = blockIdx.x * 4 + wave;     // 0..127
    int base = ch * 64;
    float an = 0.f, ap = 0.f, sn = 0.f, sp = 0.f;
    for (int kk = 0; kk < 64; ++kk) {
        int k = base + kk;
        int j = sidx[k];
        float g = Wh[(size_t)j * DD + lane];
        float wnk = wn[k], wpk = wp[k];
        an = fmaf(wnk, g, an); ap = fmaf(wpk, g, ap);
        sn += wnk; sp += wpk;
    }
    cs_neg[ch * DD + lane] = an;
    cs_pos[ch * DD + lane] = ap;
    if (lane == 0) { cs_sn[ch] = sn; cs_sp[ch] = sp; }
}

// ---------------- K4: scan the 128 chunk sums (tiny) ----------------
__global__ __launch_bounds__(64) void k_scanchunks(
    const float* __restrict__ cs_neg, const float* __restrict__ cs_pos,
    const float* __restrict__ cs_sn, const float* __restrict__ cs_sp,
    float* __restrict__ co_neg, float* __restrict__ co_pos,
    float* __restrict__ co_sn, float* __restrict__ co_sp)
{
    int lane = threadIdx.x;
    float acn = 0.f;
    for (int c = 0; c < 128; ++c) { co_neg[c * DD + lane] = acn; acn += cs_neg[c * DD + lane]; }
    float acp = 0.f;
    for (int c = 127; c >= 0; --c) { co_pos[c * DD + lane] = acp; acp += cs_pos[c * DD + lane]; }
    if (lane == 0) {
        float x = 0.f; for (int c = 0; c < 128; ++c) { co_sn[c] = x; x += cs_sn[c]; }
        float y = 0.f; for (int c = 127; c >= 0; --c) { co_sp[c] = y; y += cs_sp[c]; }
    }
}

// ---------------- K5: write full prefix (neg) / suffix (pos) arrays ----------------
__global__ __launch_bounds__(256) void k_scanwrite(
    const float* __restrict__ Wh, const int* __restrict__ sidx,
    const float* __restrict__ wn, const float* __restrict__ wp,
    const float* __restrict__ co_neg, const float* __restrict__ co_pos,
    const float* __restrict__ co_sn, const float* __restrict__ co_sp,
    float* __restrict__ P_neg, float* __restrict__ S_pos,
    float* __restrict__ s_neg, float* __restrict__ s_pos)
{
    int t = threadIdx.x, wave = t >> 6, lane = t & 63;
    int ch = blockIdx.x * 4 + wave;     // 0..127
    int base = ch * 64;

    float acc = co_neg[ch * DD + lane];
    float accs = co_sn[ch];
    for (int kk = 0; kk < 64; ++kk) {
        int k = base + kk;
        int j = sidx[k];
        float g = Wh[(size_t)j * DD + lane];
        P_neg[(size_t)k * DD + lane] = acc;
        if (lane == 0) s_neg[k] = accs;
        float wnk = wn[k];
        acc = fmaf(wnk, g, acc);
        accs += wnk;
    }
    if (ch == 127) {
        P_neg[(size_t)NN * DD + lane] = acc;
        if (lane == 0) s_neg[NN] = accs;
    }

    float accp = co_pos[ch * DD + lane];
    float accps = co_sp[ch];
    for (int kk = 63; kk >= 0; --kk) {
        int k = base + kk;
        int j = sidx[k];
        float g = Wh[(size_t)j * DD + lane];
        float wpk = wp[k];
        accp = fmaf(wpk, g, accp);
        accps += wpk;
        S_pos[(size_t)k * DD + lane] = accp;
        if (lane == 0) s_pos[k] = accps;
    }
    if (ch == 127) {
        S_pos[(size_t)NN * DD + lane] = 0.f;
        if (lane == 0) s_pos[NN] = 0.f;
    }
}

// ---------------- K6: bucket lookup + in-bucket exact correction + elu ----------------
__global__ __launch_bounds__(256) void k_out(
    const float* __restrict__ Wh, const float* __restrict__ Wh1,
    const float* __restrict__ sv, const int* __restrict__ sidx,
    const float* __restrict__ wn, const float* __restrict__ wp,
    const float* __restrict__ P_neg, const float* __restrict__ S_pos,
    const float* __restrict__ s_neg, const float* __restrict__ s_pos,
    const int* __restrict__ bstart, const float* __restrict__ meta,
    float* __restrict__ out)
{
    int t = threadIdx.x, wave = t >> 6, lane = t & 63;
    int row = blockIdx.x * 4 + wave;
    float M2 = meta[0];
    unsigned kmin = __float_as_uint(meta[1]);
    float scale = meta[2];

    float w1 = Wh1[row];
    float z = w1 + M2;                         // max_j (Wh1_i + Wh2_j)
    float m = (z >= 0.f) ? z : LRALPHA * z;    // lrelu(z) = exact row max
    float c1 = expf(z - m);                    // exponent <= 0
    float c2 = expf(LRALPHA * z - m);          // exponent <= 0
    float tt = -w1;
    unsigned kt = f2k(tt);

    int p0 = 0, p1 = 0;
    if (kt >= kmin) {
        unsigned b = bucket_of(kt, kmin, scale);
        p0 = bstart[b]; p1 = bstart[b + 1];
    }
    float num_n = P_neg[(size_t)p0 * DD + lane];
    float den_n = s_neg[p0];
    float num_p = S_pos[(size_t)p1 * DD + lane];
    float den_p = s_pos[p1];
    for (int k = p0; k < p1; ++k) {
        float vk = sv[k];
        int j = sidx[k];
        float g = Wh[(size_t)j * DD + lane];
        if (vk <= tt) { float w = wn[k]; num_n = fmaf(w, g, num_n); den_n += w; }
        else          { float w = wp[k]; num_p = fmaf(w, g, num_p); den_p += w; }
    }
    float num = c2 * num_n + c1 * num_p;
    float den = c2 * den_n + c1 * den_p;
    float r = num / den;
    out[(size_t)row * DD + lane] = (r > 0.f) ? r : expm1f(r);   // elu, alpha=1
}

extern "C" void kernel_launch(void* const* d_in, const int* in_sizes, int n_in,
                              void* d_out, int out_size, void* d_ws, size_t ws_size,
                              hipStream_t stream)
{
    const float* h = (const float*)d_in[0];
    // d_in[1] = adj (bool, unused by the reference computation)
    const float* W = (const float*)d_in[2];
    const float* a = (const float*)d_in[3];
    float* out = (float*)d_out;
    float* ws = (float*)d_ws;

    float* Wh     = ws;                              // NN*DD
    float* Wh1    = Wh + (size_t)NN * DD;            // NN
    float* Wh2    = Wh1 + NN;                        // NN
    float* sv     = Wh2 + NN;                        // NN
    float* wn     = sv + NN;                         // NN
    float* wp     = wn + NN;                         // NN
    float* s_neg  = wp + NN;                         // NN+1
    float* s_pos  = s_neg + (NN + 1);                // NN+1
    float* cs_neg = s_pos + (NN + 1);                // 128*DD
    float* cs_pos = cs_neg + 128 * DD;               // 128*DD
    float* cs_sn  = cs_pos + 128 * DD;               // 128
    float* cs_sp  = cs_sn + 128;                     // 128
    float* co_neg = cs_sp + 128;                     // 128*DD
    float* co_pos = co_neg + 128 * DD;               // 128*DD
    float* co_sn  = co_pos + 128 * DD;               // 128
    float* co_sp  = co_sn + 128;                     // 128
    float* meta   = co_sp + 128;                     // 3
    float* P_neg  = meta + 4;                        // (NN+1)*DD
    float* S_pos  = P_neg + (size_t)(NN + 1) * DD;   // (NN+1)*DD
    int*   sidx   = (int*)(S_pos + (size_t)(NN + 1) * DD);  // NN
    int*   bstart = sidx + NN;                       // NB+1

    k_gemm<<<NN / 8, 256, 0, stream>>>(h, W, a, Wh, Wh1, Wh2);
    k_bucket<<<1, 1024, 0, stream>>>(Wh2, sv, sidx, wn, wp, bstart, meta);
    k_chunksum<<<32, 256, 0, stream>>>(Wh, sidx, wn, wp, cs_neg, cs_pos, cs_sn, cs_sp);
    k_scanchunks<<<1, 64, 0, stream>>>(cs_neg, cs_pos, cs_sn, cs_sp, co_neg, co_pos, co_sn, co_sp);
    k_scanwrite<<<32, 256, 0, stream>>>(Wh, sidx, wn, wp, co_neg, co_pos, co_sn, co_sp,
                                        P_neg, S_pos, s_neg, s_pos);
    k_out<<<NN / 4, 256, 0, stream>>>(Wh, Wh1, sv, sidx, wn, wp, P_neg, S_pos,
                                      s_neg, s_pos, bstart, meta, out);
}